// Round 7
// baseline (92.985 us; speedup 1.0000x reference)
//
#include <hip/hip_runtime.h>
#include <hip/hip_bf16.h>
#include <math.h>

#define BETA_INV 20.0f          // 1/0.05
#define BG_KNN   50
#define N_CAMS   6
#define CLS      2000
#define DIM      2048
#define BATCH    256
#define NPROXY   (N_CAMS * CLS)     // 12000
#define MASK_VAL -10000.0f
#define KSPLIT   2
#define KHALF    (DIM / KSPLIT)     // 1024

typedef __attribute__((ext_vector_type(8))) short short8;
typedef __attribute__((ext_vector_type(4))) float f32x4;

__device__ __forceinline__ uint2 cvt4(float4 v) {
    uint2 r;
    asm("v_cvt_pk_bf16_f32 %0, %1, %2" : "=v"(r.x) : "v"(v.x), "v"(v.y));
    asm("v_cvt_pk_bf16_f32 %0, %1, %2" : "=v"(r.y) : "v"(v.z), "v"(v.w));
    return r;
}

// ---------------- convert feats -> bf16 (once; 65536 threads x 8 elems) ----------------
__global__ __launch_bounds__(256) void conv_a(const float* __restrict__ A,
                                              unsigned short* __restrict__ Ab)
{
    const int idx = blockIdx.x * 256 + threadIdx.x;       // 0..65535
    const float4* p = (const float4*)A + (size_t)idx * 2;
    float4 v0 = p[0], v1 = p[1];
    uint2 a = cvt4(v0), b = cvt4(v1);
    *(uint4*)(Ab + (size_t)idx * 8) = make_uint4(a.x, a.y, b.x, b.y);
}

// ---------------- GEMM (split-K x2): simsP[kh][256][12000] partials ----------------
// BM=64, BN=96, BK=64; 512 thr = 8 waves, wave tile 16x48 (1x3 frags of 16x16x32).
// Grid 1000 = 2 K-halves x 500 panels -> ~4 blocks/CU (occupancy was the limiter).
#define GBM 64
#define GBN 96
#define GBK 64
#define BSTR 72                 // Bs row stride (bf16) = 144 B -> only 2-way aliasing (free)
#define NTT (KHALF / GBK)       // 16

__global__ __launch_bounds__(512, 8) void gemm_mfma(const unsigned short* __restrict__ Ab, // [256][2048] bf16
                                                    const float* __restrict__ Bm,          // [12000][2048] f32
                                                    float* __restrict__ C)                 // [2][256][12000]
{
    __shared__ unsigned short Bs[2][GBN][BSTR];   // 27.6 KB

    const int tid = threadIdx.x;
    // bijective XCD chunk swizzle: nwg=1000 = 8 XCDs x 125. 4 M-sharers adjacent.
    const int bid = blockIdx.x;
    const int lid = (bid & 7) * 125 + (bid >> 3);
    const int kh  = lid >= 500;
    const int pid = lid - kh * 500;
    const int bm  = (pid & 3) * GBM;
    const int bn  = (pid >> 2) * GBN;
    const int kbase = kh * KHALF;

    const int lane = tid & 63, wid = tid >> 6;
    const int wm = (wid >> 1) * 16;          // 0,16,32,48
    const int wn = (wid & 1) * 48;
    const int fr = lane & 15, kg = lane >> 4;

    // A fragment pointers: pa[ks] + t*64 is the short8 for K-tile t
    const unsigned short* pa[2];
#pragma unroll
    for (int ks = 0; ks < 2; ++ks)
        pa[ks] = Ab + (size_t)(bm + wm + fr) * DIM + kbase + ks * 32 + kg * 8;

    // B staging: thread covers rows srow+32s (s=0..2), cols scol..scol+3 (fp32)
    const int srow = tid >> 4;               // 0..31
    const int scol = (tid & 15) * 4;
    const float* pb = Bm + (size_t)(bn + srow) * DIM + kbase + scol;

    f32x4 acc[3];
#pragma unroll
    for (int j = 0; j < 3; ++j) acc[j] = (f32x4){0.f, 0.f, 0.f, 0.f};

    float4 br_a[3], br_b[3];
    short8 af_a[2], af_b[2];

    // ---- prologue ----
#pragma unroll
    for (int s = 0; s < 3; ++s)
        br_a[s] = *(const float4*)(pb + (size_t)s * 32 * DIM);          // B(0)
#pragma unroll
    for (int ks = 0; ks < 2; ++ks)
        af_a[ks] = *(const short8*)(pa[ks]);                            // A(0)
#pragma unroll
    for (int s = 0; s < 3; ++s)
        *(uint2*)&Bs[0][srow + 32 * s][scol] = cvt4(br_a[s]);           // tile 0 -> LDS[0]
#pragma unroll
    for (int s = 0; s < 3; ++s)
        br_a[s] = *(const float4*)(pb + (size_t)s * 32 * DIM + 64);     // B(1) in flight
    asm volatile("s_waitcnt lgkmcnt(0)" ::: "memory");
    __builtin_amdgcn_sched_barrier(0);
    __builtin_amdgcn_s_barrier();
    __builtin_amdgcn_sched_barrier(0);

#define BODY(T, CUR, NXT, BRC, BRN, AFC, AFN) do {                                    \
    if ((T) + 2 < NTT) {                                                              \
        _Pragma("unroll")                                                             \
        for (int s = 0; s < 3; ++s)                                                   \
            BRN[s] = *(const float4*)(pb + (size_t)s * 32 * DIM + ((T) + 2) * 64);    \
    }                                                                                 \
    if ((T) + 1 < NTT) {                                                              \
        _Pragma("unroll")                                                             \
        for (int ks = 0; ks < 2; ++ks)                                                \
            AFN[ks] = *(const short8*)(pa[ks] + ((T) + 1) * 64);                      \
    }                                                                                 \
    __builtin_amdgcn_sched_barrier(0);                                                \
    _Pragma("unroll")                                                                 \
    for (int ks = 0; ks < 2; ++ks)                                                    \
        _Pragma("unroll")                                                             \
        for (int j = 0; j < 3; ++j) {                                                 \
            short8 bf = *(const short8*)&Bs[CUR][wn + j * 16 + fr][ks * 32 + kg * 8]; \
            acc[j] = __builtin_amdgcn_mfma_f32_16x16x32_bf16(AFC[ks], bf, acc[j], 0, 0, 0); \
        }                                                                             \
    if ((T) + 1 < NTT) {                                                              \
        _Pragma("unroll")                                                             \
        for (int s = 0; s < 3; ++s)                                                   \
            *(uint2*)&Bs[NXT][srow + 32 * s][scol] = cvt4(BRC[s]);                    \
    }                                                                                 \
    asm volatile("s_waitcnt lgkmcnt(0)" ::: "memory");                                \
    __builtin_amdgcn_sched_barrier(0);                                                \
    __builtin_amdgcn_s_barrier();                                                     \
    __builtin_amdgcn_sched_barrier(0);                                                \
} while (0)

    for (int t = 0; t < NTT; t += 2) {
        BODY(t,     0, 1, br_a, br_b, af_a, af_b);
        BODY(t + 1, 1, 0, br_b, br_a, af_b, af_a);
    }
#undef BODY

    // epilogue: C/D layout col=lane&15, row=(lane>>4)*4+reg
    float* Cp = C + (size_t)kh * BATCH * NPROXY;
#pragma unroll
    for (int j = 0; j < 3; ++j)
#pragma unroll
        for (int r = 0; r < 4; ++r)
            Cp[(size_t)(bm + wm + kg * 4 + r) * NPROXY + (bn + wn + j * 16 + fr)] = acc[j][r];
}

// ---------------- per-sample, register-resident (512 thr, 6x float4 each) ----------------
__device__ __forceinline__ float block_sum_f(float x, volatile float* red8, int lane, int wid) {
#pragma unroll
    for (int off = 32; off; off >>= 1) x += __shfl_xor(x, off);
    if (lane == 0) red8[wid] = x;
    __syncthreads();
    float t = 0.f;
#pragma unroll
    for (int w = 0; w < 8; ++w) t += red8[w];
    __syncthreads();
    return t;
}
__device__ __forceinline__ float block_max_f(float x, volatile float* red8, int lane, int wid) {
#pragma unroll
    for (int off = 32; off; off >>= 1) x = fmaxf(x, __shfl_xor(x, off));
    if (lane == 0) red8[wid] = x;
    __syncthreads();
    float t = -1e30f;
#pragma unroll
    for (int w = 0; w < 8; ++w) t = fmaxf(t, red8[w]);
    __syncthreads();
    return t;
}
__device__ __forceinline__ int block_sum_i(int x, volatile int* red8, int lane, int wid) {
#pragma unroll
    for (int off = 32; off; off >>= 1) x += __shfl_xor(x, off);
    if (lane == 0) red8[wid] = x;
    __syncthreads();
    int t = 0;
#pragma unroll
    for (int w = 0; w < 8; ++w) t += red8[w];
    __syncthreads();
    return t;
}

__global__ __launch_bounds__(512) void per_sample(const float* __restrict__ sims,  // [2][256][12000]
                                                  const int* __restrict__ cams,
                                                  const int* __restrict__ labels,
                                                  float* __restrict__ ce_out,
                                                  float* __restrict__ assoc_out)
{
    __shared__ float redf[8];
    __shared__ int   redi[8];
    __shared__ float pos_sh[N_CAMS];
    __shared__ float sh_vlab;

    const int i    = blockIdx.x;
    const int tid  = threadIdx.x;
    const int lane = tid & 63;
    const int wid  = tid >> 6;
    const float* s0 = sims + (size_t)i * NPROXY;
    const float* s1 = sims + (size_t)(BATCH + i) * NPROXY;
    const int cc   = cams[i];
    const int lab  = labels[i];

    float4 v[6];
#pragma unroll
    for (int ii = 0; ii < 6; ++ii) {
        int q = tid + 512 * ii;
        if (q < NPROXY / 4) {
            float4 a = *(const float4*)(s0 + 4 * q);
            float4 b = *(const float4*)(s1 + 4 * q);
            v[ii] = make_float4(a.x + b.x, a.y + b.y, a.z + b.z, a.w + b.w);
        } else v[ii] = make_float4(-1e30f, -1e30f, -1e30f, -1e30f);
    }

    const int plab = cc * CLS + lab;
    const int qlab = plab >> 2, clab = plab & 3;
#pragma unroll
    for (int ii = 0; ii < 6; ++ii) {
        if ((qlab >> 9) == ii && (qlab & 511) == tid) {
            float t = (clab == 0) ? v[ii].x : (clab == 1) ? v[ii].y : (clab == 2) ? v[ii].z : v[ii].w;
            sh_vlab = t;
        }
    }

    // ---- CE over own-camera block: q in [cc*500, cc*500+500) ----
    const int qlo = cc * 500, qhi = qlo + 500;
    float m = -1e30f;
#pragma unroll
    for (int ii = 0; ii < 6; ++ii) {
        int q = tid + 512 * ii;
        if (q >= qlo && q < qhi)
            m = fmaxf(m, fmaxf(fmaxf(v[ii].x, v[ii].y), fmaxf(v[ii].z, v[ii].w)));
    }
    const float smax = block_max_f(m, redf, lane, wid);
    float ls = 0.f;
#pragma unroll
    for (int ii = 0; ii < 6; ++ii) {
        int q = tid + 512 * ii;
        if (q >= qlo && q < qhi) {
            ls += __expf((v[ii].x - smax) * BETA_INV);
            ls += __expf((v[ii].y - smax) * BETA_INV);
            ls += __expf((v[ii].z - smax) * BETA_INV);
            ls += __expf((v[ii].w - smax) * BETA_INV);
        }
    }
    const float lsum = block_sum_f(ls, redf, lane, wid);
    if (tid == 0) ce_out[i] = logf(lsum) + (smax - sh_vlab) * BETA_INV;

    // ---- capture positives (rows j*2000+lab), mask in-register ----
#define DOPC(II, COMP, CIDX) { \
        int p = 4 * (tid + 512 * (II)) + (CIDX); \
        int r = p - lab; \
        if (r >= 0 && r <= (N_CAMS - 1) * CLS && (r % CLS) == 0) { \
            pos_sh[r / CLS] = v[II].COMP; \
            v[II].COMP = MASK_VAL; \
        } }
#pragma unroll
    for (int ii = 0; ii < 6; ++ii) {
        DOPC(ii, x, 0); DOPC(ii, y, 1); DOPC(ii, z, 2); DOPC(ii, w, 3);
    }
#undef DOPC
    __syncthreads();

    // ---- masked row max M1 ----
    float mm = -1e30f;
#pragma unroll
    for (int ii = 0; ii < 6; ++ii)
        mm = fmaxf(mm, fmaxf(fmaxf(v[ii].x, v[ii].y), fmaxf(v[ii].z, v[ii].w)));
    const float M1 = block_max_f(mm, redf, lane, wid);

    float pmax = -1e30f, psum = 0.f;
#pragma unroll
    for (int j = 0; j < N_CAMS; ++j) {
        float pv = pos_sh[j];
        pmax = fmaxf(pmax, pv);
        psum += pv;
    }

    // ---- 20-step bisection for 50th-largest (ties handled exactly below) ----
    float lo = M1 - 0.5f, hi = M1 + 1e-4f;
    int cnt_hi = 0;
    for (int it = 0; it < 20; ++it) {
        const float mid = 0.5f * (lo + hi);
        int c = 0;
#pragma unroll
        for (int ii = 0; ii < 6; ++ii) {
            c += (v[ii].x >= mid); c += (v[ii].y >= mid);
            c += (v[ii].z >= mid); c += (v[ii].w >= mid);
        }
        const int tot = block_sum_i(c, redi, lane, wid);
        if (tot >= BG_KNN) lo = mid; else { hi = mid; cnt_hi = tot; }
    }

    // ---- final: sum exp over the top-50 ----
    const float M = fmaxf(M1, pmax);
    float ss = 0.f, vt = -1e30f;
#pragma unroll
    for (int ii = 0; ii < 6; ++ii) {
#define DOF(COMP) { float x = v[ii].COMP; \
        if (x >= hi) ss += __expf((x - M) * BETA_INV); \
        else if (x >= lo) vt = fmaxf(vt, x); }
        DOF(x) DOF(y) DOF(z) DOF(w)
#undef DOF
    }
    const float ssum = block_sum_f(ss, redf, lane, wid);
    const float vtie = block_max_f(vt, redf, lane, wid);

    if (tid == 0) {
        int need = BG_KNN - cnt_hi;
        float vts = (vtie < -1e29f) ? lo : vtie;
        float total = ssum + (float)need * __expf((vts - M) * BETA_INV);
#pragma unroll
        for (int j = 0; j < N_CAMS; ++j) total += __expf((pos_sh[j] - M) * BETA_INV);
        assoc_out[i] = M * BETA_INV + logf(total) - psum * BETA_INV / (float)N_CAMS;
    }
}

// ---------------- Finalize: parallel per-camera segment means -> scalar loss ----------------
__global__ __launch_bounds__(256) void finalize(const int* __restrict__ cams,
                                                const float* __restrict__ ce,
                                                const float* __restrict__ assoc,
                                                float* __restrict__ out)
{
    __shared__ float ce_s[N_CAMS], as_s[N_CAMS];
    __shared__ int   cnt[N_CAMS];
    const int tid = threadIdx.x;
    if (tid < N_CAMS) { ce_s[tid] = 0.f; as_s[tid] = 0.f; cnt[tid] = 0; }
    __syncthreads();
    const int c = cams[tid];
    atomicAdd(&ce_s[c], ce[tid]);
    atomicAdd(&as_s[c], assoc[tid]);
    atomicAdd(&cnt[c], 1);
    __syncthreads();
    if (tid == 0) {
        float loss = 0.f;
        for (int k = 0; k < N_CAMS; ++k) {
            if (cnt[k] > 0) {
                float inv = 1.f / (float)cnt[k];
                loss += ce_s[k] * inv + 0.5f * as_s[k] * inv;
            }
        }
        out[0] = loss;
    }
}

extern "C" void kernel_launch(void* const* d_in, const int* in_sizes, int n_in,
                              void* d_out, int out_size, void* d_ws, size_t ws_size,
                              hipStream_t stream) {
    const float* feats  = (const float*)d_in[0];   // [256][2048]
    const float* mem    = (const float*)d_in[1];   // [6][2000][2048]
    const int*   cams   = (const int*)d_in[2];
    const int*   labels = (const int*)d_in[3];
    float* out = (float*)d_out;

    float* sims  = (float*)d_ws;                        // [2][256][12000] = 24.6 MB
    float* ce    = sims + (size_t)KSPLIT * BATCH * NPROXY;
    float* assoc = ce + BATCH;
    unsigned short* A_bf = (unsigned short*)(assoc + BATCH);   // 1 MB, 16B-aligned

    conv_a<<<256, 256, 0, stream>>>(feats, A_bf);
    gemm_mfma<<<1000, 512, 0, stream>>>(A_bf, mem, sims);
    per_sample<<<BATCH, 512, 0, stream>>>(sims, cams, labels, ce, assoc);
    finalize<<<1, 256, 0, stream>>>(cams, ce, assoc, out);
}